// Round 4
// baseline (520.673 us; speedup 1.0000x reference)
//
#include <hip/hip_runtime.h>
#include <hip/hip_bf16.h>
#include <stdint.h>
#include <stddef.h>

typedef __bf16 bf16x8 __attribute__((ext_vector_type(8)));
typedef float f32x16 __attribute__((ext_vector_type(16)));
typedef __hip_bfloat16 bf16_t;

#define BM 128
#define BN 128
#define BK 64
#define THREADS 256

// async global->LDS, 16B per lane. LDS dest must be wave-uniform-base + lane*16.
__device__ __forceinline__ void stage16(const void* g, void* l) {
  __builtin_amdgcn_global_load_lds(
      (const __attribute__((address_space(1))) uint32_t*)g,
      (__attribute__((address_space(3))) uint32_t*)l, 16, 0, 0);
}

__device__ __forceinline__ unsigned pk2(float x, float y) {
  bf16_t a = __float2bfloat16(x);
  bf16_t b = __float2bfloat16(y);
  unsigned short ua = *(unsigned short*)&a;
  unsigned short ub = *(unsigned short*)&b;
  return (unsigned)ua | ((unsigned)ub << 16);
}

// C = A @ Bt^T.  A: [M,K] row-major bf16.  Bt: [N,K] row-major bf16.
// OUT_MODE 0: C bf16 row-major [M,N] (ld=N)
// OUT_MODE 1: C bf16 TRANSPOSED [N,M] (ld=M)  (for support^T buffers)
// OUT_MODE 2: C f32 row-major [M,N]
// sA/sB/sC: per-batch element strides (blockIdx.z = batch).
//
// v4 core: R3's staging (row-major LDS, per-row XOR chunk swizzle, coalesced
// 8-lanes-per-row global_load_lds — measured 0 bank conflicts) + 32x32x16
// MFMA (129 cyc/wave/BK64 vs 155 for 16x16x32; epilogue math first-check
// verified in R2). Single-variable change vs R3.
template <int OUT_MODE, bool RELU>
__global__ void gemm_bt(const bf16_t* __restrict__ A, const bf16_t* __restrict__ Bt,
                        void* __restrict__ Cv, int M, int N, int K,
                        long sA, long sB, long sC) {
  __shared__ __align__(16) char lds[(BM + BN) * BK * 2];  // 32 KB
  char* ldsA = lds;
  char* ldsB = lds + BM * BK * 2;

  const int t = threadIdx.x;
  const int lane = t & 63;
  const int w = t >> 6;
  const int wm = w >> 1, wn = w & 1;   // 2x2 wave grid; each wave owns 64x64
  const int l31 = lane & 31;
  const int khalf = lane >> 5;         // k-offset 8*khalf within each K=16 step
  const int x7 = l31 & 7;              // row-XOR term for swizzled chunk lookup
  const int m0 = blockIdx.x * BM;
  const int n0 = blockIdx.y * BN;
  const int b = blockIdx.z;

  const bf16_t* Ab = A + (size_t)b * sA;
  const bf16_t* Bb = Bt + (size_t)b * sB;

  // Staging (unchanged from R1/R3): tile = 128 rows x 64 bf16 = 1024 16B-chunks;
  // 4 insts x 256 threads. LDS chunk (r, kc) holds global chunk (r, kc ^ (r&7)).
  size_t aSrc[4], bSrc[4];
#pragma unroll
  for (int i = 0; i < 4; ++i) {
    int c = i * 256 + t;
    int r = c >> 3;
    int kcs = (c & 7) ^ (r & 7);
    aSrc[i] = (size_t)(m0 + r) * K + (size_t)kcs * 8;
    bSrc[i] = (size_t)(n0 + r) * K + (size_t)kcs * 8;
  }

  f32x16 acc[2][2];
#pragma unroll
  for (int mi = 0; mi < 2; ++mi)
#pragma unroll
    for (int ni = 0; ni < 2; ++ni)
      acc[mi][ni] = (f32x16)(0.f);

  const int aRow = wm * 64 + l31;      // fragment row within tile (+ mi*32)
  const int bRow = wn * 64 + l31;

  for (int k0 = 0; k0 < K; k0 += BK) {
#pragma unroll
    for (int i = 0; i < 4; ++i) {
      stage16(Ab + aSrc[i] + k0, ldsA + (i * 256 + t) * 16);
      stage16(Bb + bSrc[i] + k0, ldsB + (i * 256 + t) * 16);
    }
    __syncthreads();

#pragma unroll
    for (int ks = 0; ks < 4; ++ks) {   // four K=16 MFMA steps per BK=64
      // lane reads row (aRow + mi*32), k-chunk (ks*2+khalf), stored swizzled:
      // chunk pos = (ks*2+khalf) ^ (row&7); row&7 == l31&7 == x7 (mi*32 = 0 mod 8)
      const int xo = ((((ks << 1) | khalf) ^ x7) << 4);
      bf16x8 af[2], bfr[2];
#pragma unroll
      for (int mi = 0; mi < 2; ++mi)
        af[mi] = *(const bf16x8*)(ldsA + (aRow + mi * 32) * 128 + xo);
#pragma unroll
      for (int ni = 0; ni < 2; ++ni)
        bfr[ni] = *(const bf16x8*)(ldsB + (bRow + ni * 32) * 128 + xo);
#pragma unroll
      for (int mi = 0; mi < 2; ++mi)
#pragma unroll
        for (int ni = 0; ni < 2; ++ni)
          acc[mi][ni] = __builtin_amdgcn_mfma_f32_32x32x16_bf16(
              af[mi], bfr[ni], acc[mi][ni], 0, 0, 0);
    }
    __syncthreads();
  }

  // Epilogue (verified: R2 first-check passed, absmax == R1's). 32x32 C/D layout
  // (m74/m101): col = lane&31, row = (reg&3) + 8*(reg>>2) + 4*(lane>>5).
  if (OUT_MODE == 1) {
    bf16_t* Ct = (bf16_t*)Cv + (size_t)b * sC;
#pragma unroll
    for (int mi = 0; mi < 2; ++mi) {
#pragma unroll
      for (int ni = 0; ni < 2; ++ni) {
        int nIdx = n0 + wn * 64 + ni * 32 + l31;       // row of C^T
        size_t rowOff = (size_t)nIdx * (size_t)M;
        int mBase = m0 + wm * 64 + mi * 32 + 4 * khalf;
#pragma unroll
        for (int g = 0; g < 4; ++g) {                  // regs 4g..4g+3 -> m..m+3
          float v0 = acc[mi][ni][4 * g + 0];
          float v1 = acc[mi][ni][4 * g + 1];
          float v2 = acc[mi][ni][4 * g + 2];
          float v3 = acc[mi][ni][4 * g + 3];
          if (RELU) {
            v0 = fmaxf(v0, 0.f); v1 = fmaxf(v1, 0.f);
            v2 = fmaxf(v2, 0.f); v3 = fmaxf(v3, 0.f);
          }
          uint2 pkv;
          pkv.x = pk2(v0, v1);
          pkv.y = pk2(v2, v3);
          *(uint2*)(Ct + rowOff + mBase + 8 * g) = pkv;
        }
      }
    }
  } else if (OUT_MODE == 0) {
    bf16_t* C = (bf16_t*)Cv + (size_t)b * sC;
#pragma unroll
    for (int mi = 0; mi < 2; ++mi) {
#pragma unroll
      for (int ni = 0; ni < 2; ++ni) {
        int col = n0 + wn * 64 + ni * 32 + l31;
        int mBase = m0 + wm * 64 + mi * 32 + 4 * khalf;
#pragma unroll
        for (int j = 0; j < 16; ++j) {
          int row = mBase + (j & 3) + 8 * (j >> 2);
          float v = acc[mi][ni][j];
          if (RELU) v = fmaxf(v, 0.f);
          C[(size_t)row * (size_t)N + col] = __float2bfloat16(v);
        }
      }
    }
  } else {
    float* C = (float*)Cv + (size_t)b * sC;
#pragma unroll
    for (int mi = 0; mi < 2; ++mi) {
#pragma unroll
      for (int ni = 0; ni < 2; ++ni) {
        int col = n0 + wn * 64 + ni * 32 + l31;
        int mBase = m0 + wm * 64 + mi * 32 + 4 * khalf;
#pragma unroll
        for (int j = 0; j < 16; ++j) {
          int row = mBase + (j & 3) + 8 * (j >> 2);
          float v = acc[mi][ni][j];
          if (RELU) v = fmaxf(v, 0.f);
          C[(size_t)row * (size_t)N + col] = v;
        }
      }
    }
  }
}

// o = bf16(a * s), 4 elems/thread
__global__ void mul_cast_kernel(const float* __restrict__ a, const float* __restrict__ s,
                                bf16_t* __restrict__ o, int n4) {
  int i = blockIdx.x * blockDim.x + threadIdx.x;
  if (i < n4) {
    float4 av = ((const float4*)a)[i];
    float4 sv = ((const float4*)s)[i];
    uint2 r;
    r.x = pk2(av.x * sv.x, av.y * sv.y);
    r.y = pk2(av.z * sv.z, av.w * sv.w);
    ((uint2*)o)[i] = r;
  }
}

__global__ void cast_kernel(const float* __restrict__ a, bf16_t* __restrict__ o, int n4) {
  int i = blockIdx.x * blockDim.x + threadIdx.x;
  if (i < n4) {
    float4 av = ((const float4*)a)[i];
    uint2 r;
    r.x = pk2(av.x, av.y);
    r.y = pk2(av.z, av.w);
    ((uint2*)o)[i] = r;
  }
}

// All three weight transposes in one launch.
// wt[h*K + k] = bf16(w[k*H + h]); ranges laid out flat.
__global__ void transpose_cast3_kernel(const float* __restrict__ W1, const float* __restrict__ W2,
                                       const float* __restrict__ W3, bf16_t* __restrict__ W1T,
                                       bf16_t* __restrict__ W2T, bf16_t* __restrict__ W3T) {
  const int n1 = 256 * 512;          // W1
  const int n2 = 512 * 1024;         // W2
  const int n3 = 1024 * 256;         // W3
  int idx = blockIdx.x * blockDim.x + threadIdx.x;
  if (idx < n1) {
    int K = 256, H = 512;
    int h = idx / K, k = idx - h * K;
    W1T[idx] = __float2bfloat16(W1[(size_t)k * H + h]);
  } else if (idx < n1 + n2) {
    int i = idx - n1;
    int K = 512, H = 1024;
    int h = i / K, k = i - h * K;
    W2T[i] = __float2bfloat16(W2[(size_t)k * H + h]);
  } else if (idx < n1 + n2 + n3) {
    int i = idx - n1 - n2;
    int K = 1024, H = 256;
    int h = i / K, k = i - h * K;
    W3T[i] = __float2bfloat16(W3[(size_t)k * H + h]);
  }
}

extern "C" void kernel_launch(void* const* d_in, const int* in_sizes, int n_in,
                              void* d_out, int out_size, void* d_ws, size_t ws_size,
                              hipStream_t stream) {
  const float* x   = (const float*)d_in[0];  // [4, 4096, 256]
  const float* adj = (const float*)d_in[1];  // [4096, 4096]
  const float* S   = (const float*)d_in[2];  // [4096, 4096]
  const float* W1  = (const float*)d_in[3];  // [256, 512]
  const float* W2  = (const float*)d_in[4];  // [512, 1024]
  const float* W3  = (const float*)d_in[5];  // [1024, 256]

  const int N = 4096, F = 256, H1 = 512, H2 = 1024, NC = 256, B = 4;

  // R3-verified compact ping-pong workspace (97.8 MiB). Do not grow.
  char* ws = (char*)d_ws;
  bf16_t* AW  = (bf16_t*)ws; ws += (size_t)N * N * 2;       // bf16(adj*S)
  bf16_t* P1  = (bf16_t*)ws; ws += (size_t)B * H2 * N * 2;  // support^T buffers
  bf16_t* P2  = (bf16_t*)ws; ws += (size_t)B * N * H2 * 2;  // XB -> h1 -> h2
  bf16_t* W1T = (bf16_t*)ws; ws += (size_t)F * H1 * 2;      // [512,256]
  bf16_t* W2T = (bf16_t*)ws; ws += (size_t)H1 * H2 * 2;     // [1024,512]
  bf16_t* W3T = (bf16_t*)ws; ws += (size_t)H2 * NC * 2;     // [256,1024]

  bf16_t* XB = P2;  // x cast to bf16, dead after gemm1

  // prep
  mul_cast_kernel<<<(N * N / 4 + 255) / 256, 256, 0, stream>>>(adj, S, AW, N * N / 4);
  cast_kernel<<<(B * N * F / 4 + 255) / 256, 256, 0, stream>>>(x, XB, B * N * F / 4);
  {
    int total = 256 * 512 + 512 * 1024 + 1024 * 256;
    transpose_cast3_kernel<<<(total + 255) / 256, 256, 0, stream>>>(W1, W2, W3, W1T, W2T, W3T);
  }

  dim3 blk(THREADS);

  // layer 1: st1^T[H1,N] = (XB @ W1)^T -> P1 ; h1 = relu(AW @ st1) -> P2
  gemm_bt<1, false><<<dim3(N / BM, H1 / BN, B), blk, 0, stream>>>(
      XB, W1T, P1, N, H1, F, (long)N * F, 0, (long)H1 * N);
  gemm_bt<0, true><<<dim3(N / BM, H1 / BN, B), blk, 0, stream>>>(
      AW, P1, P2, N, H1, N, 0, (long)H1 * N, (long)N * H1);

  // layer 2: st2^T[H2,N] = (h1 @ W2)^T -> P1 ; h2 = relu(AW @ st2) -> P2
  gemm_bt<1, false><<<dim3(N / BM, H2 / BN, B), blk, 0, stream>>>(
      P2, W2T, P1, N, H2, H1, (long)N * H1, 0, (long)H2 * N);
  gemm_bt<0, true><<<dim3(N / BM, H2 / BN, B), blk, 0, stream>>>(
      AW, P1, P2, N, H2, N, 0, (long)H2 * N, (long)N * H2);

  // layer 3: st3^T[NC,N] = (h2 @ W3)^T -> P1 ; out = AW @ st3 (fp32) -> d_out
  gemm_bt<1, false><<<dim3(N / BM, NC / BN, B), blk, 0, stream>>>(
      P2, W3T, P1, N, NC, H2, (long)N * H2, 0, (long)NC * N);
  gemm_bt<2, false><<<dim3(N / BM, NC / BN, B), blk, 0, stream>>>(
      AW, P1, d_out, N, NC, N, 0, (long)NC * N, (long)N * NC);
}

// Round 5
// 420.301 us; speedup vs baseline: 1.2388x; 1.2388x over previous
//
#include <hip/hip_runtime.h>
#include <hip/hip_bf16.h>
#include <stdint.h>
#include <stddef.h>

typedef __bf16 bf16x8 __attribute__((ext_vector_type(8)));
typedef float f32x4 __attribute__((ext_vector_type(4)));
typedef __hip_bfloat16 bf16_t;

#define BM 128
#define BN 128
#define BK 64
#define THREADS 256

// async global->LDS, 16B per lane. LDS dest must be wave-uniform-base + lane*16.
__device__ __forceinline__ void stage16(const void* g, void* l) {
  __builtin_amdgcn_global_load_lds(
      (const __attribute__((address_space(1))) uint32_t*)g,
      (__attribute__((address_space(3))) uint32_t*)l, 16, 0, 0);
}

__device__ __forceinline__ unsigned pk2(float x, float y) {
  bf16_t a = __float2bfloat16(x);
  bf16_t b = __float2bfloat16(y);
  unsigned short ua = *(unsigned short*)&a;
  unsigned short ub = *(unsigned short*)&b;
  return (unsigned)ua | ((unsigned)ub << 16);
}

// C = A @ Bt^T.  A: [M,K] row-major bf16.  Bt: [N,K] row-major bf16.
// OUT_MODE 0: C bf16 row-major [M,N] (ld=N)
// OUT_MODE 1: C bf16 TRANSPOSED [N,M] (ld=M)
// OUT_MODE 2: C f32 row-major [M,N]
// sA/sB/sC: per-batch element strides (blockIdx.z = batch).
// R3-verified core: 16x16x32 MFMA, row-major LDS with per-row XOR chunk
// swizzle (measured 0 bank conflicts), coalesced 8-lanes-per-row
// global_load_lds staging. DO NOT MODIFY (R4's 32-row fragment variant
// produced 1.7e7 bank conflicts; this layout is verified only for
// 16-row fragments).
template <int OUT_MODE, bool RELU>
__global__ void gemm_bt(const bf16_t* __restrict__ A, const bf16_t* __restrict__ Bt,
                        void* __restrict__ Cv, int M, int N, int K,
                        long sA, long sB, long sC) {
  __shared__ __align__(16) char lds[(BM + BN) * BK * 2];  // 32 KB
  char* ldsA = lds;
  char* ldsB = lds + BM * BK * 2;

  const int t = threadIdx.x;
  const int lane = t & 63;
  const int w = t >> 6;
  const int wm = w >> 1, wn = w & 1;          // 2x2 wave grid, each wave 64x64
  const int quad = lane >> 4, l15 = lane & 15;
  const int m0 = blockIdx.x * BM;
  const int n0 = blockIdx.y * BN;
  const int b = blockIdx.z;

  const bf16_t* Ab = A + (size_t)b * sA;
  const bf16_t* Bb = Bt + (size_t)b * sB;

  // Staging: tile = 128 rows x 64 bf16 = 1024 16B-chunks; 4 insts x 256 threads.
  // XOR-swizzle: LDS chunk (r, kc) holds global chunk (r, kc ^ (r&7)).
  size_t aSrc[4], bSrc[4];
#pragma unroll
  for (int i = 0; i < 4; ++i) {
    int c = i * 256 + t;
    int r = c >> 3;
    int kcs = (c & 7) ^ (r & 7);
    aSrc[i] = (size_t)(m0 + r) * K + (size_t)kcs * 8;
    bSrc[i] = (size_t)(n0 + r) * K + (size_t)kcs * 8;
  }

  f32x4 acc[4][4];
#pragma unroll
  for (int mi = 0; mi < 4; ++mi)
#pragma unroll
    for (int ni = 0; ni < 4; ++ni)
      acc[mi][ni] = f32x4{0.f, 0.f, 0.f, 0.f};

  const int aRowB = (wm * 64 + l15) * (BK * 2);   // byte offset of this lane's A row
  const int bRowB = (wn * 64 + l15) * (BK * 2);
  const int xc0 = (quad ^ (lane & 7)) * 16;       // swizzled k-chunk byte offset, ks=0

  for (int k0 = 0; k0 < K; k0 += BK) {
#pragma unroll
    for (int i = 0; i < 4; ++i) {
      stage16(Ab + aSrc[i] + k0, ldsA + (i * 256 + t) * 16);
      stage16(Bb + bSrc[i] + k0, ldsB + (i * 256 + t) * 16);
    }
    __syncthreads();

#pragma unroll
    for (int ks = 0; ks < 2; ++ks) {            // two K=32 MFMA steps per BK=64
      const int xo = xc0 ^ (ks * 64);
      bf16x8 af[4], bfr[4];
#pragma unroll
      for (int mi = 0; mi < 4; ++mi)
        af[mi] = *(const bf16x8*)(ldsA + aRowB + mi * 2048 + xo);
#pragma unroll
      for (int ni = 0; ni < 4; ++ni)
        bfr[ni] = *(const bf16x8*)(ldsB + bRowB + ni * 2048 + xo);
#pragma unroll
      for (int mi = 0; mi < 4; ++mi)
#pragma unroll
        for (int ni = 0; ni < 4; ++ni)
          acc[mi][ni] = __builtin_amdgcn_mfma_f32_16x16x32_bf16(
              af[mi], bfr[ni], acc[mi][ni], 0, 0, 0);
    }
    __syncthreads();
  }

  // Epilogue. C/D layout (verified m89/m91): col = lane&15, row = quad*4 + reg.
  const int mBase = m0 + wm * 64 + quad * 4;
  const int nBase = n0 + wn * 64 + l15;

  if (OUT_MODE == 1) {
    bf16_t* Ct = (bf16_t*)Cv + (size_t)b * sC;
#pragma unroll
    for (int ni = 0; ni < 4; ++ni) {
      size_t colOff = (size_t)(nBase + ni * 16) * (size_t)M;
#pragma unroll
      for (int mi = 0; mi < 4; ++mi) {
        int rr = mBase + mi * 16;
        float v0 = acc[mi][ni][0], v1 = acc[mi][ni][1];
        float v2 = acc[mi][ni][2], v3 = acc[mi][ni][3];
        if (RELU) {
          v0 = fmaxf(v0, 0.f); v1 = fmaxf(v1, 0.f);
          v2 = fmaxf(v2, 0.f); v3 = fmaxf(v3, 0.f);
        }
        uint2 pkv;
        pkv.x = pk2(v0, v1);
        pkv.y = pk2(v2, v3);
        *(uint2*)(Ct + colOff + rr) = pkv;
      }
    }
  } else if (OUT_MODE == 0) {
    bf16_t* C = (bf16_t*)Cv + (size_t)b * sC;
#pragma unroll
    for (int mi = 0; mi < 4; ++mi) {
#pragma unroll
      for (int j = 0; j < 4; ++j) {
        size_t rowOff = (size_t)(mBase + mi * 16 + j) * (size_t)N;
#pragma unroll
        for (int ni = 0; ni < 4; ++ni) {
          float v = acc[mi][ni][j];
          if (RELU) v = fmaxf(v, 0.f);
          C[rowOff + nBase + ni * 16] = __float2bfloat16(v);
        }
      }
    }
  } else {
    float* C = (float*)Cv + (size_t)b * sC;
#pragma unroll
    for (int mi = 0; mi < 4; ++mi) {
#pragma unroll
      for (int j = 0; j < 4; ++j) {
        size_t rowOff = (size_t)(mBase + mi * 16 + j) * (size_t)N;
#pragma unroll
        for (int ni = 0; ni < 4; ++ni) {
          float v = acc[mi][ni][j];
          if (RELU) v = fmaxf(v, 0.f);
          C[rowOff + nBase + ni * 16] = v;
        }
      }
    }
  }
}

// o = bf16(a * s), 4 elems/thread
__global__ void mul_cast_kernel(const float* __restrict__ a, const float* __restrict__ s,
                                bf16_t* __restrict__ o, int n4) {
  int i = blockIdx.x * blockDim.x + threadIdx.x;
  if (i < n4) {
    float4 av = ((const float4*)a)[i];
    float4 sv = ((const float4*)s)[i];
    uint2 r;
    r.x = pk2(av.x * sv.x, av.y * sv.y);
    r.y = pk2(av.z * sv.z, av.w * sv.w);
    ((uint2*)o)[i] = r;
  }
}

// x [B][4096][256] f32 -> xt [B][256][4096] bf16, 32x32 LDS tiles, coalesced both sides.
__global__ void transpose_cast_x(const float* __restrict__ x, bf16_t* __restrict__ xt) {
  __shared__ float tile[32][33];
  const int N = 4096, F = 256;
  int n0 = blockIdx.x * 32, f0 = blockIdx.y * 32, b = blockIdx.z;
  const float* xb = x + (size_t)b * N * F;
  bf16_t* xtb = xt + (size_t)b * N * F;
  int tx = threadIdx.x & 31, ty = threadIdx.x >> 5;  // 32 x 8
#pragma unroll
  for (int i = 0; i < 32; i += 8)
    tile[ty + i][tx] = xb[(size_t)(n0 + ty + i) * F + f0 + tx];
  __syncthreads();
#pragma unroll
  for (int i = 0; i < 32; i += 8)
    xtb[(size_t)(f0 + ty + i) * N + n0 + tx] = __float2bfloat16(tile[tx][ty + i]);
}

// All three weight transposes in one launch. wt[h*K + k] = bf16(w[k*H + h]).
__global__ void transpose_cast3_kernel(const float* __restrict__ W1, const float* __restrict__ W2,
                                       const float* __restrict__ W3, bf16_t* __restrict__ W1T,
                                       bf16_t* __restrict__ W2T, bf16_t* __restrict__ W3T) {
  const int n1 = 256 * 512;
  const int n2 = 512 * 1024;
  const int n3 = 1024 * 256;
  int idx = blockIdx.x * blockDim.x + threadIdx.x;
  if (idx < n1) {
    int K = 256, H = 512;
    int h = idx / K, k = idx - h * K;
    W1T[idx] = __float2bfloat16(W1[(size_t)k * H + h]);
  } else if (idx < n1 + n2) {
    int i = idx - n1;
    int K = 512, H = 1024;
    int h = i / K, k = i - h * K;
    W2T[i] = __float2bfloat16(W2[(size_t)k * H + h]);
  } else if (idx < n1 + n2 + n3) {
    int i = idx - n1 - n2;
    int K = 1024, H = 256;
    int h = i / K, k = i - h * K;
    W3T[i] = __float2bfloat16(W3[(size_t)k * H + h]);
  }
}

extern "C" void kernel_launch(void* const* d_in, const int* in_sizes, int n_in,
                              void* d_out, int out_size, void* d_ws, size_t ws_size,
                              hipStream_t stream) {
  const float* x   = (const float*)d_in[0];  // [4, 4096, 256]
  const float* adj = (const float*)d_in[1];  // [4096, 4096]
  const float* S   = (const float*)d_in[2];  // [4096, 4096]
  const float* W1  = (const float*)d_in[3];  // [256, 512]
  const float* W2  = (const float*)d_in[4];  // [512, 1024]
  const float* W3  = (const float*)d_in[5];  // [1024, 256]

  const int N = 4096, F = 256, H1 = 512, H2 = 1024, NC = 256, B = 4;

  // Associativity-optimized chain (167.6 GF vs 270.6):
  //   L1: g1 = AW @ x        ; h1 = relu(g1 @ W1)   (adj-first: 256 < 512)
  //   L2: g2 = AW @ h1       ; h2 = relu(g2 @ W2)   (adj-first: 512 < 1024)
  //   L3: st3 = h2 @ W3      ; out = AW @ st3       (support-first: 1024 > 256)
  //
  // Workspace (~102.5 MiB; R1's 121.8 passed, stay under):
  //   BufX: XBT (8.4 of 33.5) -> h2 (33.5)
  //   BufY: g1 (8.4) -> g2 (16.8) -> st3T (8.4)
  //   BufZ: h1T (16.8)
  char* ws = (char*)d_ws;
  bf16_t* AW   = (bf16_t*)ws; ws += (size_t)N * N * 2;       // 33.5 MB
  bf16_t* BufX = (bf16_t*)ws; ws += (size_t)B * N * H2 * 2;  // 33.5 MB
  bf16_t* BufY = (bf16_t*)ws; ws += (size_t)B * N * H1 * 2;  // 16.8 MB
  bf16_t* BufZ = (bf16_t*)ws; ws += (size_t)B * N * H1 * 2;  // 16.8 MB
  bf16_t* W1T  = (bf16_t*)ws; ws += (size_t)F * H1 * 2;
  bf16_t* W2T  = (bf16_t*)ws; ws += (size_t)H1 * H2 * 2;
  bf16_t* W3T  = (bf16_t*)ws; ws += (size_t)H2 * NC * 2;

  bf16_t* XBT  = BufX;  // x^T bf16 [B][256][4096], dead after g1
  bf16_t* G1   = BufY;  // [B][4096][256]
  bf16_t* H1T  = BufZ;  // [B][512][4096]
  bf16_t* G2   = BufY;  // [B][4096][512] (overwrites G1, dead)
  bf16_t* H2B  = BufX;  // [B][4096][1024] (overwrites XBT, dead)
  bf16_t* ST3T = BufY;  // [B][256][4096] (overwrites G2, dead)

  // prep
  mul_cast_kernel<<<(N * N / 4 + 255) / 256, 256, 0, stream>>>(adj, S, AW, N * N / 4);
  transpose_cast_x<<<dim3(N / 32, F / 32, B), 256, 0, stream>>>(x, XBT);
  {
    int total = 256 * 512 + 512 * 1024 + 1024 * 256;
    transpose_cast3_kernel<<<(total + 255) / 256, 256, 0, stream>>>(W1, W2, W3, W1T, W2T, W3T);
  }

  dim3 blk(THREADS);

  // L1: g1 = AW @ x   (Bt = x^T [256,4096]) -> G1 [4096,256] row-major
  gemm_bt<0, false><<<dim3(N / BM, F / BN, B), blk, 0, stream>>>(
      AW, XBT, G1, N, F, N, 0, (long)F * N, (long)N * F);
  //     h1^T = (g1 @ W1)^T with relu -> H1T [512,4096]
  gemm_bt<1, true><<<dim3(N / BM, H1 / BN, B), blk, 0, stream>>>(
      G1, W1T, H1T, N, H1, F, (long)N * F, 0, (long)H1 * N);

  // L2: g2 = AW @ h1  (Bt = h1^T [512,4096]) -> G2 [4096,512] row-major
  gemm_bt<0, false><<<dim3(N / BM, H1 / BN, B), blk, 0, stream>>>(
      AW, H1T, G2, N, H1, N, 0, (long)H1 * N, (long)N * H1);
  //     h2 = relu(g2 @ W2) -> H2B [4096,1024] row-major
  gemm_bt<0, true><<<dim3(N / BM, H2 / BN, B), blk, 0, stream>>>(
      G2, W2T, H2B, N, H2, H1, (long)N * H1, 0, (long)N * H2);

  // L3: st3^T = (h2 @ W3)^T -> ST3T [256,4096]
  gemm_bt<1, false><<<dim3(N / BM, NC / BN, B), blk, 0, stream>>>(
      H2B, W3T, ST3T, N, NC, H2, (long)N * H2, 0, (long)NC * N);
  //     out = AW @ st3 (fp32) -> d_out [4096,256]
  gemm_bt<2, false><<<dim3(N / BM, NC / BN, B), blk, 0, stream>>>(
      AW, ST3T, d_out, N, NC, N, 0, (long)NC * N, (long)N * NC);
}

// Round 6
// 389.373 us; speedup vs baseline: 1.3372x; 1.0794x over previous
//
#include <hip/hip_runtime.h>
#include <hip/hip_bf16.h>
#include <stdint.h>
#include <stddef.h>

typedef __bf16 bf16x8 __attribute__((ext_vector_type(8)));
typedef float f32x4 __attribute__((ext_vector_type(4)));
typedef __hip_bfloat16 bf16_t;

#define BM 128
#define BN 128
#define BK 64
#define THREADS 256

// async global->LDS, 16B per lane. LDS dest must be wave-uniform-base + lane*16.
__device__ __forceinline__ void stage16(const void* g, void* l) {
  __builtin_amdgcn_global_load_lds(
      (const __attribute__((address_space(1))) uint32_t*)g,
      (__attribute__((address_space(3))) uint32_t*)l, 16, 0, 0);
}

__device__ __forceinline__ unsigned pk2(float x, float y) {
  bf16_t a = __float2bfloat16(x);
  bf16_t b = __float2bfloat16(y);
  unsigned short ua = *(unsigned short*)&a;
  unsigned short ub = *(unsigned short*)&b;
  return (unsigned)ua | ((unsigned)ub << 16);
}

// C = A @ Bt^T.  A: [M,K] row-major bf16.  Bt: [N,K] row-major bf16.
// OUT_MODE 0: C bf16 row-major [M,N] (ld=N)
// OUT_MODE 1: C bf16 TRANSPOSED [N,M] (ld=M)
// OUT_MODE 2: C f32 row-major [M,N]
// Split-K: blockIdx.z = kz*4 + b (B=4 hardcoded). K = row stride of A/Bt;
// Kc = this block's K-extent (Kc==K => no split). Output chunk = z*sC,
// so partial chunks land at consecutive sC strides for the reduce kernel.
// R3-verified core: 16x16x32 MFMA, row-major LDS with per-row XOR chunk
// swizzle (measured 0 bank conflicts), coalesced 8-lanes-per-row
// global_load_lds staging. DO NOT MODIFY the staging/LDS-read scheme
// (R4's 32-row fragment variant produced 1.7e7 bank conflicts).
template <int OUT_MODE, bool RELU>
__global__ void gemm_bt(const bf16_t* __restrict__ A, const bf16_t* __restrict__ Bt,
                        void* __restrict__ Cv, int M, int N, int K, int Kc,
                        long sA, long sB, long sC) {
  __shared__ __align__(16) char lds[(BM + BN) * BK * 2];  // 32 KB
  char* ldsA = lds;
  char* ldsB = lds + BM * BK * 2;

  const int t = threadIdx.x;
  const int lane = t & 63;
  const int w = t >> 6;
  const int wm = w >> 1, wn = w & 1;          // 2x2 wave grid, each wave 64x64
  const int quad = lane >> 4, l15 = lane & 15;
  const int m0 = blockIdx.x * BM;
  const int n0 = blockIdx.y * BN;
  const int z = blockIdx.z;
  const int b = z & 3;                        // batch (B=4)
  const int kz = z >> 2;                      // split-K chunk

  const bf16_t* Ab = A + (size_t)b * sA + (size_t)kz * Kc;
  const bf16_t* Bb = Bt + (size_t)b * sB + (size_t)kz * Kc;

  // Staging: tile = 128 rows x 64 bf16 = 1024 16B-chunks; 4 insts x 256 threads.
  // XOR-swizzle: LDS chunk (r, kc) holds global chunk (r, kc ^ (r&7)).
  size_t aSrc[4], bSrc[4];
#pragma unroll
  for (int i = 0; i < 4; ++i) {
    int c = i * 256 + t;
    int r = c >> 3;
    int kcs = (c & 7) ^ (r & 7);
    aSrc[i] = (size_t)(m0 + r) * K + (size_t)kcs * 8;
    bSrc[i] = (size_t)(n0 + r) * K + (size_t)kcs * 8;
  }

  f32x4 acc[4][4];
#pragma unroll
  for (int mi = 0; mi < 4; ++mi)
#pragma unroll
    for (int ni = 0; ni < 4; ++ni)
      acc[mi][ni] = f32x4{0.f, 0.f, 0.f, 0.f};

  const int aRowB = (wm * 64 + l15) * (BK * 2);
  const int bRowB = (wn * 64 + l15) * (BK * 2);
  const int xc0 = (quad ^ (lane & 7)) * 16;

  for (int k0 = 0; k0 < Kc; k0 += BK) {
#pragma unroll
    for (int i = 0; i < 4; ++i) {
      stage16(Ab + aSrc[i] + k0, ldsA + (i * 256 + t) * 16);
      stage16(Bb + bSrc[i] + k0, ldsB + (i * 256 + t) * 16);
    }
    __syncthreads();

#pragma unroll
    for (int ks = 0; ks < 2; ++ks) {
      const int xo = xc0 ^ (ks * 64);
      bf16x8 af[4], bfr[4];
#pragma unroll
      for (int mi = 0; mi < 4; ++mi)
        af[mi] = *(const bf16x8*)(ldsA + aRowB + mi * 2048 + xo);
#pragma unroll
      for (int ni = 0; ni < 4; ++ni)
        bfr[ni] = *(const bf16x8*)(ldsB + bRowB + ni * 2048 + xo);
#pragma unroll
      for (int mi = 0; mi < 4; ++mi)
#pragma unroll
        for (int ni = 0; ni < 4; ++ni)
          acc[mi][ni] = __builtin_amdgcn_mfma_f32_16x16x32_bf16(
              af[mi], bfr[ni], acc[mi][ni], 0, 0, 0);
    }
    __syncthreads();
  }

  // Epilogue. C/D layout (verified m89/m91): col = lane&15, row = quad*4 + reg.
  const int mBase = m0 + wm * 64 + quad * 4;
  const int nBase = n0 + wn * 64 + l15;

  if (OUT_MODE == 1) {
    bf16_t* Ct = (bf16_t*)Cv + (size_t)z * sC;
#pragma unroll
    for (int ni = 0; ni < 4; ++ni) {
      size_t colOff = (size_t)(nBase + ni * 16) * (size_t)M;
#pragma unroll
      for (int mi = 0; mi < 4; ++mi) {
        int rr = mBase + mi * 16;
        float v0 = acc[mi][ni][0], v1 = acc[mi][ni][1];
        float v2 = acc[mi][ni][2], v3 = acc[mi][ni][3];
        if (RELU) {
          v0 = fmaxf(v0, 0.f); v1 = fmaxf(v1, 0.f);
          v2 = fmaxf(v2, 0.f); v3 = fmaxf(v3, 0.f);
        }
        uint2 pkv;
        pkv.x = pk2(v0, v1);
        pkv.y = pk2(v2, v3);
        *(uint2*)(Ct + colOff + rr) = pkv;
      }
    }
  } else if (OUT_MODE == 0) {
    bf16_t* C = (bf16_t*)Cv + (size_t)z * sC;
#pragma unroll
    for (int mi = 0; mi < 4; ++mi) {
#pragma unroll
      for (int j = 0; j < 4; ++j) {
        size_t rowOff = (size_t)(mBase + mi * 16 + j) * (size_t)N;
#pragma unroll
        for (int ni = 0; ni < 4; ++ni) {
          float v = acc[mi][ni][j];
          if (RELU) v = fmaxf(v, 0.f);
          C[rowOff + nBase + ni * 16] = __float2bfloat16(v);
        }
      }
    }
  } else {
    float* C = (float*)Cv + (size_t)z * sC;
#pragma unroll
    for (int mi = 0; mi < 4; ++mi) {
#pragma unroll
      for (int j = 0; j < 4; ++j) {
        size_t rowOff = (size_t)(mBase + mi * 16 + j) * (size_t)N;
#pragma unroll
        for (int ni = 0; ni < 4; ++ni) {
          float v = acc[mi][ni][j];
          if (RELU) v = fmaxf(v, 0.f);
          C[rowOff + nBase + ni * 16] = v;
        }
      }
    }
  }
}

// Sum SK bf16 partial chunks (stride tot elements) in fp32; write bf16 or f32.
// 8 elements per thread; tot must be a multiple of 8*256 (all our sizes are).
template <int SK, bool F32OUT>
__global__ void reduce_k(const bf16_t* __restrict__ pp, void* __restrict__ out,
                         size_t tot) {
  size_t i = ((size_t)blockIdx.x * blockDim.x + threadIdx.x) * 8;
  if (i >= tot) return;
  float s[8] = {0.f, 0.f, 0.f, 0.f, 0.f, 0.f, 0.f, 0.f};
#pragma unroll
  for (int kz = 0; kz < SK; ++kz) {
    bf16x8 v = *(const bf16x8*)(pp + kz * tot + i);
#pragma unroll
    for (int j = 0; j < 8; ++j) s[j] += (float)v[j];
  }
  if (F32OUT) {
    float* o = (float*)out + i;
#pragma unroll
    for (int j = 0; j < 8; ++j) o[j] = s[j];
  } else {
    uint4 r;
    r.x = pk2(s[0], s[1]);
    r.y = pk2(s[2], s[3]);
    r.z = pk2(s[4], s[5]);
    r.w = pk2(s[6], s[7]);
    *(uint4*)((bf16_t*)out + i) = r;
  }
}

// o = bf16(a * s), 4 elems/thread
__global__ void mul_cast_kernel(const float* __restrict__ a, const float* __restrict__ s,
                                bf16_t* __restrict__ o, int n4) {
  int i = blockIdx.x * blockDim.x + threadIdx.x;
  if (i < n4) {
    float4 av = ((const float4*)a)[i];
    float4 sv = ((const float4*)s)[i];
    uint2 r;
    r.x = pk2(av.x * sv.x, av.y * sv.y);
    r.y = pk2(av.z * sv.z, av.w * sv.w);
    ((uint2*)o)[i] = r;
  }
}

// x [B][4096][256] f32 -> xt [B][256][4096] bf16, 32x32 LDS tiles.
__global__ void transpose_cast_x(const float* __restrict__ x, bf16_t* __restrict__ xt) {
  __shared__ float tile[32][33];
  const int N = 4096, F = 256;
  int n0 = blockIdx.x * 32, f0 = blockIdx.y * 32, b = blockIdx.z;
  const float* xb = x + (size_t)b * N * F;
  bf16_t* xtb = xt + (size_t)b * N * F;
  int tx = threadIdx.x & 31, ty = threadIdx.x >> 5;  // 32 x 8
#pragma unroll
  for (int i = 0; i < 32; i += 8)
    tile[ty + i][tx] = xb[(size_t)(n0 + ty + i) * F + f0 + tx];
  __syncthreads();
#pragma unroll
  for (int i = 0; i < 32; i += 8)
    xtb[(size_t)(f0 + ty + i) * N + n0 + tx] = __float2bfloat16(tile[tx][ty + i]);
}

// All three weight transposes in one launch. wt[h*K + k] = bf16(w[k*H + h]).
__global__ void transpose_cast3_kernel(const float* __restrict__ W1, const float* __restrict__ W2,
                                       const float* __restrict__ W3, bf16_t* __restrict__ W1T,
                                       bf16_t* __restrict__ W2T, bf16_t* __restrict__ W3T) {
  const int n1 = 256 * 512;
  const int n2 = 512 * 1024;
  const int n3 = 1024 * 256;
  int idx = blockIdx.x * blockDim.x + threadIdx.x;
  if (idx < n1) {
    int K = 256, H = 512;
    int h = idx / K, k = idx - h * K;
    W1T[idx] = __float2bfloat16(W1[(size_t)k * H + h]);
  } else if (idx < n1 + n2) {
    int i = idx - n1;
    int K = 512, H = 1024;
    int h = i / K, k = i - h * K;
    W2T[i] = __float2bfloat16(W2[(size_t)k * H + h]);
  } else if (idx < n1 + n2 + n3) {
    int i = idx - n1 - n2;
    int K = 1024, H = 256;
    int h = i / K, k = i - h * K;
    W3T[i] = __float2bfloat16(W3[(size_t)k * H + h]);
  }
}

extern "C" void kernel_launch(void* const* d_in, const int* in_sizes, int n_in,
                              void* d_out, int out_size, void* d_ws, size_t ws_size,
                              hipStream_t stream) {
  const float* x   = (const float*)d_in[0];  // [4, 4096, 256]
  const float* adj = (const float*)d_in[1];  // [4096, 4096]
  const float* S   = (const float*)d_in[2];  // [4096, 4096]
  const float* W1  = (const float*)d_in[3];  // [256, 512]
  const float* W2  = (const float*)d_in[4];  // [512, 1024]
  const float* W3  = (const float*)d_in[5];  // [1024, 256]

  const int N = 4096, F = 256, H1 = 512, H2 = 1024, NC = 256, B = 4;

  // Associativity-optimized chain (167.6 GF) + split-K on grid-starved GEMMs:
  //   L1: g1 = AW @ x (SK=4) ; h1^T = (g1 @ W1)^T relu
  //   L2: g2 = AW @ h1 (SK=2); h2 = relu(g2 @ W2)
  //   L3: st3^T = (h2 @ W3)^T (SK=2); out = AW @ st3 (SK=4, fp32)
  //
  // Workspace 110.9 MiB (< R1's passing 121.8):
  //   SCR time-shares: g1 partials -> g2 partials -> H2B -> out partials.
  //   BufZ time-shares: H1T -> st3T partials.
  //   BufY time-shares: G1 -> G2 -> ST3T.
  char* ws = (char*)d_ws;
  bf16_t* AW   = (bf16_t*)ws; ws += (size_t)N * N * 2;       // 33.5 MB
  bf16_t* SCR  = (bf16_t*)ws; ws += (size_t)B * N * H2 * 2;  // 33.5 MB
  bf16_t* XBT  = (bf16_t*)ws; ws += (size_t)B * N * F * 2;   //  8.4 MB
  bf16_t* BufY = (bf16_t*)ws; ws += (size_t)B * N * H1 * 2;  // 16.8 MB
  bf16_t* BufZ = (bf16_t*)ws; ws += (size_t)B * N * H1 * 2;  // 16.8 MB
  bf16_t* W1T  = (bf16_t*)ws; ws += (size_t)F * H1 * 2;
  bf16_t* W2T  = (bf16_t*)ws; ws += (size_t)H1 * H2 * 2;
  bf16_t* W3T  = (bf16_t*)ws; ws += (size_t)H2 * NC * 2;

  bf16_t* G1   = BufY;  // [B][4096][256]
  bf16_t* H1T  = BufZ;  // [B][512][4096]
  bf16_t* G2   = BufY;  // [B][4096][512]
  bf16_t* H2B  = SCR;   // [B][4096][1024]
  bf16_t* ST3T = BufY;  // [B][256][4096]

  // prep
  mul_cast_kernel<<<(N * N / 4 + 255) / 256, 256, 0, stream>>>(adj, S, AW, N * N / 4);
  transpose_cast_x<<<dim3(N / 32, F / 32, B), 256, 0, stream>>>(x, XBT);
  {
    int total = 256 * 512 + 512 * 1024 + 1024 * 256;
    transpose_cast3_kernel<<<(total + 255) / 256, 256, 0, stream>>>(W1, W2, W3, W1T, W2T, W3T);
  }

  dim3 blk(THREADS);

  // L1: g1 = AW @ x, SK=4 -> partials in SCR, reduce -> G1
  gemm_bt<0, false><<<dim3(N / BM, F / BN, B * 4), blk, 0, stream>>>(
      AW, XBT, SCR, N, F, N, N / 4, 0, (long)F * N, (long)N * F);
  reduce_k<4, false><<<(B * N * F / 8) / 256, 256, 0, stream>>>(
      SCR, G1, (size_t)B * N * F);
  //     h1^T = (g1 @ W1)^T relu -> H1T [512,4096]
  gemm_bt<1, true><<<dim3(N / BM, H1 / BN, B), blk, 0, stream>>>(
      G1, W1T, H1T, N, H1, F, F, (long)N * F, 0, (long)H1 * N);

  // L2: g2 = AW @ h1, SK=2 -> partials in SCR, reduce -> G2
  gemm_bt<0, false><<<dim3(N / BM, H1 / BN, B * 2), blk, 0, stream>>>(
      AW, H1T, SCR, N, H1, N, N / 2, 0, (long)H1 * N, (long)N * H1);
  reduce_k<2, false><<<(B * N * H1 / 8) / 256, 256, 0, stream>>>(
      SCR, G2, (size_t)B * N * H1);
  //     h2 = relu(g2 @ W2) -> H2B (SCR; g2 partials dead after reduce)
  gemm_bt<0, true><<<dim3(N / BM, H2 / BN, B), blk, 0, stream>>>(
      G2, W2T, H2B, N, H2, H1, H1, (long)N * H1, 0, (long)N * H2);

  // L3: st3^T = (h2 @ W3)^T, SK=2 -> partials in BufZ (H1T dead), reduce -> ST3T
  gemm_bt<1, false><<<dim3(N / BM, NC / BN, B * 2), blk, 0, stream>>>(
      H2B, W3T, BufZ, N, NC, H2, H2 / 2, (long)N * H2, 0, (long)NC * N);
  reduce_k<2, false><<<(B * NC * N / 8) / 256, 256, 0, stream>>>(
      BufZ, ST3T, (size_t)B * NC * N);
  //     out = AW @ st3, SK=4 -> partials in SCR (H2B dead), reduce fp32 -> d_out
  gemm_bt<0, false><<<dim3(N / BM, NC / BN, B * 4), blk, 0, stream>>>(
      AW, ST3T, SCR, N, NC, N, N / 4, 0, (long)NC * N, (long)N * NC);
  reduce_k<4, true><<<(B * N * NC / 8) / 256, 256, 0, stream>>>(
      SCR, d_out, (size_t)B * N * NC);
}